// Round 1
// baseline (1418.984 us; speedup 1.0000x reference)
//
#include <hip/hip_runtime.h>

// FeastNet: B=2, V=50000, NB=16, C=64, K=8, O=64
// out[b,v,o] = inv_deg[v] * sum_{c,k} M[c,k] * W[c, k*O+o]
//   M[c,k]   = sum_n patches[b,v,n,c] * q[b,v,n,k]
//   q        = softmax_k( xu[b,v,k] - xu[b,adj[v,n]-1,k] ),  xu = x @ u
//   masked (adj==0): q forced to 0, patch row clamped to 0 (contribution dies)

#define NB 16
#define CC 64
#define KK 8
#define OO 64
constexpr int BB = 2;
constexpr int VV = 50000;

// ---------------- K0: xu[b,v,k] = sum_c x[b,v,c] * u[c,k] ----------------
__global__ void xu_kernel(const float* __restrict__ x,
                          const float* __restrict__ u,
                          float* __restrict__ xu, int total) {
    int t = blockIdx.x * blockDim.x + threadIdx.x;
    if (t >= total) return;
    const float4* xr = reinterpret_cast<const float4*>(x + (size_t)t * CC);
    float acc[KK];
#pragma unroll
    for (int k = 0; k < KK; ++k) acc[k] = 0.f;
#pragma unroll
    for (int c4 = 0; c4 < CC / 4; ++c4) {
        float4 xv = xr[c4];
#pragma unroll
        for (int k = 0; k < KK; ++k) {
            acc[k] = fmaf(xv.x, u[(c4 * 4 + 0) * KK + k], acc[k]);
            acc[k] = fmaf(xv.y, u[(c4 * 4 + 1) * KK + k], acc[k]);
            acc[k] = fmaf(xv.z, u[(c4 * 4 + 2) * KK + k], acc[k]);
            acc[k] = fmaf(xv.w, u[(c4 * 4 + 3) * KK + k], acc[k]);
        }
    }
    float4* xo = reinterpret_cast<float4*>(xu + (size_t)t * KK);
    xo[0] = make_float4(acc[0], acc[1], acc[2], acc[3]);
    xo[1] = make_float4(acc[4], acc[5], acc[6], acc[7]);
}

// ---------------- K2: fused q + M + W-contraction ----------------
// One thread per (b, v). q[16][8], acc[64], double-buffered patch float4s
// in VGPRs (~350). W read through uniform indices -> scalar loads.

#define CONSUME(P, C4IDX)                                                     \
    {                                                                         \
        _Pragma("unroll") for (int cc = 0; cc < 4; ++cc) {                    \
            float pv[NB];                                                     \
            _Pragma("unroll") for (int n = 0; n < NB; ++n) {                  \
                pv[n] = (cc == 0 ? P[n].x                                     \
                                 : cc == 1 ? P[n].y : cc == 2 ? P[n].z        \
                                                              : P[n].w);      \
            }                                                                 \
            float m8[KK];                                                     \
            _Pragma("unroll") for (int k = 0; k < KK; ++k) m8[k] = 0.f;       \
            _Pragma("unroll") for (int n = 0; n < NB; ++n) {                  \
                _Pragma("unroll") for (int k = 0; k < KK; ++k) {              \
                    m8[k] = fmaf(pv[n], q[n][k], m8[k]);                      \
                }                                                             \
            }                                                                 \
            const float* Wr = W + ((C4IDX) * 4 + cc) * (KK * OO);             \
            _Pragma("unroll") for (int k = 0; k < KK; ++k) {                  \
                _Pragma("unroll") for (int o = 0; o < OO; ++o) {              \
                    acc[o] = fmaf(m8[k], Wr[k * OO + o], acc[o]);             \
                }                                                             \
            }                                                                 \
        }                                                                     \
    }

__global__ __launch_bounds__(256, 1) void feast_main(
    const float* __restrict__ x, const float* __restrict__ W,
    const int* __restrict__ adj, const float* __restrict__ xu,
    float* __restrict__ out) {
    int v = blockIdx.x * blockDim.x + threadIdx.x;
    if (v >= VV) return;
    int b = blockIdx.y;

    // adj row (64B aligned, vector loads)
    int a[NB];
    const int4* arow = reinterpret_cast<const int4*>(adj + (size_t)v * NB);
#pragma unroll
    for (int n4 = 0; n4 < NB / 4; ++n4) {
        int4 t4 = arow[n4];
        a[n4 * 4 + 0] = t4.x;
        a[n4 * 4 + 1] = t4.y;
        a[n4 * 4 + 2] = t4.z;
        a[n4 * 4 + 3] = t4.w;
    }

    float deg = 0.f;
    int off4[NB];   // float4-index of neighbor row in x
    int xoff2[NB];  // float4-index of neighbor row in xu (2 per row)
#pragma unroll
    for (int n = 0; n < NB; ++n) {
        bool act = (a[n] != 0);
        deg += act ? 1.f : 0.f;
        int row = act ? (a[n] - 1) : 0;
        int g = b * VV + row;
        off4[n] = g * (CC / 4);
        xoff2[n] = g * (KK / 4);
    }

    const float4* x4 = reinterpret_cast<const float4*>(x);
    const float4* xu4 = reinterpret_cast<const float4*>(xu);

    // self xu row
    int gs = b * VV + v;
    float4 s0 = xu4[gs * 2 + 0], s1 = xu4[gs * 2 + 1];
    float xs[KK] = {s0.x, s0.y, s0.z, s0.w, s1.x, s1.y, s1.z, s1.w};

    // q[n][k] = softmax over k of (xu_self - xu_neighbor); masked n -> 0
    float q[NB][KK];
#pragma unroll
    for (int n = 0; n < NB; ++n) {
        float4 n0 = xu4[xoff2[n] + 0], n1 = xu4[xoff2[n] + 1];
        float l[KK] = {xs[0] - n0.x, xs[1] - n0.y, xs[2] - n0.z, xs[3] - n0.w,
                       xs[4] - n1.x, xs[5] - n1.y, xs[6] - n1.z, xs[7] - n1.w};
        float mx = l[0];
#pragma unroll
        for (int k = 1; k < KK; ++k) mx = fmaxf(mx, l[k]);
        float e[KK];
        float sum = 0.f;
#pragma unroll
        for (int k = 0; k < KK; ++k) {
            e[k] = expf(l[k] - mx);
            sum += e[k];
        }
        float r = (a[n] != 0) ? (1.f / sum) : 0.f;
#pragma unroll
        for (int k = 0; k < KK; ++k) q[n][k] = e[k] * r;
    }

    // main loop over channel quads, ping-pong prefetch of patch columns
    float acc[OO];
#pragma unroll
    for (int o = 0; o < OO; ++o) acc[o] = 0.f;

    float4 pa[NB], pb[NB];
#pragma unroll
    for (int n = 0; n < NB; ++n) pa[n] = x4[off4[n] + 0];

#pragma unroll 1
    for (int c4 = 0; c4 < CC / 4; c4 += 2) {
#pragma unroll
        for (int n = 0; n < NB; ++n) pb[n] = x4[off4[n] + c4 + 1];
        CONSUME(pa, c4)
        if (c4 + 2 < CC / 4) {
#pragma unroll
            for (int n = 0; n < NB; ++n) pa[n] = x4[off4[n] + c4 + 2];
        }
        CONSUME(pb, (c4 + 1))
    }

    float invd = (deg > 0.f) ? (1.f / deg) : 0.f;
    float4* orow = reinterpret_cast<float4*>(out + ((size_t)b * VV + v) * OO);
#pragma unroll
    for (int o4 = 0; o4 < OO / 4; ++o4)
        orow[o4] = make_float4(acc[o4 * 4 + 0] * invd, acc[o4 * 4 + 1] * invd,
                               acc[o4 * 4 + 2] * invd, acc[o4 * 4 + 3] * invd);
}

extern "C" void kernel_launch(void* const* d_in, const int* in_sizes, int n_in,
                              void* d_out, int out_size, void* d_ws,
                              size_t ws_size, hipStream_t stream) {
    const float* x = (const float*)d_in[0];    // (B,V,C) f32
    const float* u = (const float*)d_in[1];    // (C,K)   f32
    const float* W = (const float*)d_in[2];    // (C,K*O) f32
    const int* adj = (const int*)d_in[3];      // (V,NB)  i32
    float* out = (float*)d_out;                // (B,V,O) f32
    float* xu = (float*)d_ws;                  // (B*V,K) f32 = 3.2 MB scratch

    int total = BB * VV;
    xu_kernel<<<(total + 255) / 256, 256, 0, stream>>>(x, u, xu, total);
    dim3 g((VV + 255) / 256, BB);
    feast_main<<<g, 256, 0, stream>>>(x, W, adj, xu, out);
}

// Round 3
// 177.555 us; speedup vs baseline: 7.9918x; 7.9918x over previous
//
#include <hip/hip_runtime.h>
#include <hip/hip_bf16.h>

// FeastNet fused: B=2, V=50000, NB=16, C=64, K=8, O=64
// out[b,v,o] = inv_deg[v] * sum_{c,k} M[c,k] * W[c,k,o]
//   M[c,k]   = sum_n patches[b,v,n,c] * q[b,v,n,k]
//   q        = softmax_k( xu[self] - xu[neighbor] ),  xu = x @ u  (3.2MB ws)
// Phase 1: 8 threads/vertex build M (fp32 acc) -> bf16 LDS (XOR-swizzled).
// Phase 2: 4-wave MFMA GEMM  out[32v x 64o] = M[32 x 512] @ Wb[512 x 64].
// W pre-converted to bf16 in MFMA B-fragment order (64KB, L2-resident).

constexpr int BB = 2;
constexpr int VV = 50000;
#define NB 16
#define CC 64
#define KK 8
#define OO 64
#define TV 32  // vertices per workgroup

typedef __attribute__((ext_vector_type(8))) short bf16x8;  // 8 bf16 (4 VGPRs)
typedef __attribute__((ext_vector_type(4))) float f32x4;

static __device__ __forceinline__ short f2b(float f) {
    __hip_bfloat16 h = __float2bfloat16(f);  // RNE
    return *reinterpret_cast<short*>(&h);
}

// ---------------- K0: xu[g,k] = sum_c x[g,c] * u[c,k] ----------------
__global__ void xu_kernel(const float* __restrict__ x,
                          const float* __restrict__ u,
                          float* __restrict__ xu, int total) {
    int t = blockIdx.x * blockDim.x + threadIdx.x;
    if (t >= total) return;
    const float4* xr = reinterpret_cast<const float4*>(x + (size_t)t * CC);
    float acc[KK];
#pragma unroll
    for (int k = 0; k < KK; ++k) acc[k] = 0.f;
#pragma unroll
    for (int c4 = 0; c4 < CC / 4; ++c4) {
        float4 xv = xr[c4];
#pragma unroll
        for (int k = 0; k < KK; ++k) {
            acc[k] = fmaf(xv.x, u[(c4 * 4 + 0) * KK + k], acc[k]);
            acc[k] = fmaf(xv.y, u[(c4 * 4 + 1) * KK + k], acc[k]);
            acc[k] = fmaf(xv.z, u[(c4 * 4 + 2) * KK + k], acc[k]);
            acc[k] = fmaf(xv.w, u[(c4 * 4 + 3) * KK + k], acc[k]);
        }
    }
    float4* xo = reinterpret_cast<float4*>(xu + (size_t)t * KK);
    xo[0] = make_float4(acc[0], acc[1], acc[2], acc[3]);
    xo[1] = make_float4(acc[4], acc[5], acc[6], acc[7]);
}

// -------- K1: W (C,K*O) f32 -> Wb bf16 in MFMA B-fragment order --------
// B-frag (16x16x32, B is 32x16): lane l holds col = l&15, k = (l>>4)*8 + e.
// dst layout: Wb[((ks*4 + gct)*64 + l)*8 + e], ck = ks*32 + (l>>4)*8 + e,
//             o = gct*16 + (l&15), src = ck*OO + o.
__global__ void wprep_kernel(const float* __restrict__ W,
                             short* __restrict__ Wb) {
    int dst = blockIdx.x * blockDim.x + threadIdx.x;  // 32768 total
    int e = dst & 7;
    int l = (dst >> 3) & 63;
    int ctk = dst >> 9;       // 0..63
    int gct = ctk & 3;        // col tile 0..3
    int ks = ctk >> 2;        // k-step 0..15
    int ck = ks * 32 + (l >> 4) * 8 + e;
    int o = gct * 16 + (l & 15);
    Wb[dst] = f2b(W[ck * OO + o]);
}

// ---------------- K2: fused M-build + MFMA contraction ----------------
__global__ __launch_bounds__(256, 3) void feast_fused(
    const float* __restrict__ x, const int* __restrict__ adj,
    const float* __restrict__ xu, const short* __restrict__ Wb,
    float* __restrict__ out) {
    __shared__ short Mlds[TV * 512];  // 32KB, row = 1024B = 64 16B-slots
    __shared__ float sInvd[TV];

    int t = threadIdx.x;
    int b = blockIdx.y;
    int v0 = blockIdx.x * TV;

    // ================= Phase 1: build M for 32 vertices =================
    {
        int vl = t >> 3;  // vertex local 0..31
        int j = t & 7;    // channel-octet 0..7 (c = j*8 .. j*8+7)
        int v = v0 + vl;
        if (v >= VV) v = VV - 1;

        int a[NB];
        const int4* arow = reinterpret_cast<const int4*>(adj + (size_t)v * NB);
#pragma unroll
        for (int n4 = 0; n4 < NB / 4; ++n4) {
            int4 t4 = arow[n4];
            a[n4 * 4 + 0] = t4.x;
            a[n4 * 4 + 1] = t4.y;
            a[n4 * 4 + 2] = t4.z;
            a[n4 * 4 + 3] = t4.w;
        }

        const float4* xu4 = reinterpret_cast<const float4*>(xu);
        const float4* x4 = reinterpret_cast<const float4*>(x);
        int gs = b * VV + v;
        float4 s0 = xu4[gs * 2 + 0], s1 = xu4[gs * 2 + 1];
        float xs[KK] = {s0.x, s0.y, s0.z, s0.w, s1.x, s1.y, s1.z, s1.w};

        float acc[8][KK];
#pragma unroll
        for (int c = 0; c < 8; ++c)
#pragma unroll
            for (int k = 0; k < KK; ++k) acc[c][k] = 0.f;
        float deg = 0.f;

#pragma unroll 4
        for (int n = 0; n < NB; ++n) {
            int an = a[n];
            bool act = (an != 0);
            deg += act ? 1.f : 0.f;
            int row = act ? (an - 1) : 0;
            int g = b * VV + row;
            // logits + softmax (fp32)
            float4 n0 = xu4[g * 2 + 0], n1 = xu4[g * 2 + 1];
            float l8[KK] = {xs[0] - n0.x, xs[1] - n0.y, xs[2] - n0.z,
                            xs[3] - n0.w, xs[4] - n1.x, xs[5] - n1.y,
                            xs[6] - n1.z, xs[7] - n1.w};
            float mx = l8[0];
#pragma unroll
            for (int k = 1; k < KK; ++k) mx = fmaxf(mx, l8[k]);
            float sum = 0.f;
            float e8[KK];
#pragma unroll
            for (int k = 0; k < KK; ++k) {
                e8[k] = __expf(l8[k] - mx);
                sum += e8[k];
            }
            float r = act ? (1.f / sum) : 0.f;
            float qk[KK];
#pragma unroll
            for (int k = 0; k < KK; ++k) qk[k] = e8[k] * r;
            // patch chunk: channels j*8 .. j*8+7
            float4 p0 = x4[(size_t)g * 16 + j * 2 + 0];
            float4 p1 = x4[(size_t)g * 16 + j * 2 + 1];
            float p[8] = {p0.x, p0.y, p0.z, p0.w, p1.x, p1.y, p1.z, p1.w};
#pragma unroll
            for (int c = 0; c < 8; ++c)
#pragma unroll
                for (int k = 0; k < KK; ++k)
                    acc[c][k] = fmaf(p[c], qk[k], acc[c][k]);
        }

        if (j == 0) sInvd[vl] = (deg > 0.f) ? (1.f / deg) : 0.f;

        // write M row vl: K-dim index ck = (j*8+c)*8 + k; thread covers
        // bytes [j*128, j*128+128) = slots j*8 .. j*8+7, XOR-swizzled.
#pragma unroll
        for (int s = 0; s < 8; ++s) {
            bf16x8 w;
#pragma unroll
            for (int k = 0; k < KK; ++k) w[k] = f2b(acc[s][k]);
            int slot = (j * 8 + s) ^ (vl & 7);
            *reinterpret_cast<bf16x8*>(
                reinterpret_cast<char*>(Mlds) + vl * 1024 + slot * 16) = w;
        }
    }
    __syncthreads();

    // ============ Phase 2: out[32x64] = M[32x512] @ Wb[512x64] ============
    {
        int wid = t >> 6;  // wave 0..3
        int l = t & 63;
        int rt = wid >> 1;  // row tile (16 rows)
        int ch = wid & 1;   // col half (32 cols)
        int r = rt * 16 + (l & 15);

        f32x4 acc2[2];
        acc2[0] = (f32x4){0.f, 0.f, 0.f, 0.f};
        acc2[1] = (f32x4){0.f, 0.f, 0.f, 0.f};
        const bf16x8* WbV = reinterpret_cast<const bf16x8*>(Wb);

#pragma unroll
        for (int ks = 0; ks < 16; ++ks) {
            int slotA = (ks * 4 + (l >> 4)) ^ (r & 7);
            bf16x8 afrag = *reinterpret_cast<const bf16x8*>(
                reinterpret_cast<const char*>(Mlds) + r * 1024 + slotA * 16);
#pragma unroll
            for (int ct = 0; ct < 2; ++ct) {
                int gct = ch * 2 + ct;
                bf16x8 bfrag = WbV[(ks * 4 + gct) * 64 + l];
                acc2[ct] = __builtin_amdgcn_mfma_f32_16x16x32_bf16(
                    afrag, bfrag, acc2[ct], 0, 0, 0);
            }
        }

        // epilogue: C/D layout col = l&15, row = (l>>4)*4 + reg
#pragma unroll
        for (int ct = 0; ct < 2; ++ct) {
            int col = ch * 32 + ct * 16 + (l & 15);
#pragma unroll
            for (int jr = 0; jr < 4; ++jr) {
                int rowl = rt * 16 + (l >> 4) * 4 + jr;
                int vv = v0 + rowl;
                if (vv < VV) {
                    out[((size_t)b * VV + vv) * OO + col] =
                        acc2[ct][jr] * sInvd[rowl];
                }
            }
        }
    }
}

extern "C" void kernel_launch(void* const* d_in, const int* in_sizes, int n_in,
                              void* d_out, int out_size, void* d_ws,
                              size_t ws_size, hipStream_t stream) {
    const float* x = (const float*)d_in[0];  // (B,V,C) f32
    const float* u = (const float*)d_in[1];  // (C,K)   f32
    const float* W = (const float*)d_in[2];  // (C,K*O) f32
    const int* adj = (const int*)d_in[3];    // (V,NB)  i32
    float* out = (float*)d_out;              // (B,V,O) f32

    float* xu = (float*)d_ws;  // (B*V, K) f32 = 3.2 MB
    short* Wb = (short*)((char*)d_ws + (size_t)BB * VV * KK * sizeof(float));

    int total = BB * VV;
    xu_kernel<<<(total + 255) / 256, 256, 0, stream>>>(x, u, xu, total);
    wprep_kernel<<<(CC * KK * OO) / 256, 256, 0, stream>>>(W, Wb);
    dim3 g((VV + TV - 1) / TV, BB);
    feast_fused<<<g, 256, 0, stream>>>(x, adj, xu, Wb, out);
}